// Round 1
// 566.032 us; speedup vs baseline: 1.0855x; 1.0855x over previous
//
#include <hip/hip_runtime.h>

#define H 4096
#define O 4096
#define HO 8192
#define MAXLEN 15

// Two-row wave dot: rows w0,w1 (length 4*n4 floats) against shared x.
// Two independent weight streams per wave -> 2x memory-level parallelism,
// x loaded once for both rows.
__device__ __forceinline__ void wave_dot2(const float* __restrict__ w0,
                                          const float* __restrict__ w1,
                                          const float* __restrict__ x,
                                          int n4, int lane,
                                          float& r0, float& r1) {
    const float4* a  = (const float4*)w0;
    const float4* b  = (const float4*)w1;
    const float4* xx = (const float4*)x;
    float acc0 = 0.f, acc1 = 0.f;
    #pragma unroll 4
    for (int i = lane; i < n4; i += 64) {
        float4 xv = xx[i];
        float4 av = a[i];
        float4 bv = b[i];
        acc0 += av.x * xv.x + av.y * xv.y + av.z * xv.z + av.w * xv.w;
        acc1 += bv.x * xv.x + bv.y * xv.y + bv.z * xv.z + bv.w * xv.w;
    }
    #pragma unroll
    for (int off = 32; off; off >>= 1) {
        acc0 += __shfl_down(acc0, off, 64);
        acc1 += __shfl_down(acc1, off, 64);
    }
    r0 = acc0; r1 = acc1;
}

// K1a: att logits. One block per attention row (15 blocks x 1024 threads).
// 1024 threads * 2 float4 each covers the 8192-wide row exactly.
__global__ __launch_bounds__(1024) void k_attlogit(const int* __restrict__ ids,
                                                   const float* __restrict__ hidden,
                                                   const float* __restrict__ embW,
                                                   const float* __restrict__ attW,
                                                   const float* __restrict__ attb,
                                                   float* __restrict__ attlog) {
    __shared__ float sred[16];
    const int tid = threadIdx.x, lane = tid & 63, wave = tid >> 6;
    const int j = blockIdx.x;
    const float* emb = embW + (size_t)ids[0] * O;
    const float4* w4 = (const float4*)(attW + (size_t)j * (H + O));
    const float4* e4 = (const float4*)emb;
    const float4* h4 = (const float4*)hidden;

    float4 wv0 = w4[tid];          // emb half: float4 idx 0..1023
    float4 xv0 = e4[tid];
    float4 wv1 = w4[tid + 1024];   // hidden half
    float4 xv1 = h4[tid];
    float acc = wv0.x * xv0.x + wv0.y * xv0.y + wv0.z * xv0.z + wv0.w * xv0.w
              + wv1.x * xv1.x + wv1.y * xv1.y + wv1.z * xv1.z + wv1.w * xv1.w;
    #pragma unroll
    for (int off = 32; off; off >>= 1) acc += __shfl_down(acc, off, 64);
    if (lane == 0) sred[wave] = acc;
    __syncthreads();
    if (tid == 0) {
        float s = 0.f;
        #pragma unroll
        for (int w = 0; w < 16; w++) s += sred[w];
        attlog[j] = s + attb[j];
    }
}

// K1b: softmax(15) computed redundantly per thread (L2-hot scalar reads),
// att_applied into combined[O:], emb copy into combined[0:O], attw output.
// grid 16 x 256 = 4096 threads, one output element each.
__global__ __launch_bounds__(256) void k_attapply(const int* __restrict__ ids,
                                                  const float* __restrict__ embW,
                                                  const float* __restrict__ attlog,
                                                  const float* __restrict__ eseq,
                                                  float* __restrict__ combined,
                                                  float* __restrict__ out_attw) {
    const int k = blockIdx.x * 256 + threadIdx.x;   // 0..4095
    float l[MAXLEN];
    float m = -1e30f;
    #pragma unroll
    for (int j = 0; j < MAXLEN; j++) { l[j] = attlog[j]; m = fmaxf(m, l[j]); }
    float s = 0.f;
    #pragma unroll
    for (int j = 0; j < MAXLEN; j++) { l[j] = __expf(l[j] - m); s += l[j]; }
    const float inv = 1.f / s;

    float acc = 0.f;
    #pragma unroll
    for (int j = 0; j < MAXLEN; j++) acc += l[j] * eseq[j * H + k];
    combined[O + k] = acc * inv;
    combined[k] = embW[(size_t)ids[0] * O + k];
    if (blockIdx.x == 0 && threadIdx.x < MAXLEN) out_attw[threadIdx.x] = l[threadIdx.x] * inv;
}

// K2: x = relu(comb_W @ combined + b) and gh = gru_W_hh @ h0 + b_hh.
// 512 threads = 8 waves, 2 rows/wave -> 16 rows per block.
// blocks [0,256): comb rows; [256,1024): ghh rows.
__global__ __launch_bounds__(512) void k_mv1(const float* __restrict__ combW,
                                             const float* __restrict__ combB,
                                             const float* __restrict__ ghhW,
                                             const float* __restrict__ ghhB,
                                             const float* __restrict__ hidden,
                                             const float* __restrict__ combined,
                                             float* __restrict__ xout,
                                             float* __restrict__ ghout) {
    const int wave = threadIdx.x >> 6, lane = threadIdx.x & 63;
    const int b = blockIdx.x;
    float r0, r1;
    if (b < 256) {
        const int row = b * 16 + wave * 2;           // 0..4094
        wave_dot2(combW + (size_t)row * HO, combW + (size_t)(row + 1) * HO,
                  combined, HO >> 2, lane, r0, r1);
        if (lane == 0) {
            xout[row]     = fmaxf(r0 + combB[row], 0.f);
            xout[row + 1] = fmaxf(r1 + combB[row + 1], 0.f);
        }
    } else {
        const int row = (b - 256) * 16 + wave * 2;   // 0..12286
        wave_dot2(ghhW + (size_t)row * H, ghhW + (size_t)(row + 1) * H,
                  hidden, H >> 2, lane, r0, r1);
        if (lane == 0) {
            ghout[row]     = r0 + ghhB[row];
            ghout[row + 1] = r1 + ghhB[row + 1];
        }
    }
}

// K3: gi = gru_W_ih @ x (3 gate rows per wave, fused 3-stream loop), gate math, h_new.
__global__ __launch_bounds__(256) void k_gru(const float* __restrict__ gihW,
                                             const float* __restrict__ gihB,
                                             const float* __restrict__ hidden,
                                             const float* __restrict__ x,
                                             const float* __restrict__ gh,
                                             float* __restrict__ hout,
                                             float* __restrict__ out_h) {
    const int wave = threadIdx.x >> 6, lane = threadIdx.x & 63;
    const int i = blockIdx.x * 4 + wave;             // 0..4095
    const float4* w0 = (const float4*)(gihW + (size_t)i * H);
    const float4* w1 = (const float4*)(gihW + (size_t)(i + H) * H);
    const float4* w2 = (const float4*)(gihW + (size_t)(i + 2 * H) * H);
    const float4* x4 = (const float4*)x;
    float a0 = 0.f, a1 = 0.f, a2 = 0.f;
    #pragma unroll 4
    for (int t = lane; t < (H >> 2); t += 64) {
        float4 xv = x4[t];
        float4 v0 = w0[t];
        float4 v1 = w1[t];
        float4 v2 = w2[t];
        a0 += v0.x * xv.x + v0.y * xv.y + v0.z * xv.z + v0.w * xv.w;
        a1 += v1.x * xv.x + v1.y * xv.y + v1.z * xv.z + v1.w * xv.w;
        a2 += v2.x * xv.x + v2.y * xv.y + v2.z * xv.z + v2.w * xv.w;
    }
    #pragma unroll
    for (int off = 32; off; off >>= 1) {
        a0 += __shfl_down(a0, off, 64);
        a1 += __shfl_down(a1, off, 64);
        a2 += __shfl_down(a2, off, 64);
    }
    if (lane == 0) {
        float ir = a0 + gihB[i];
        float iz = a1 + gihB[i + H];
        float in_ = a2 + gihB[i + 2 * H];
        float hr = gh[i], hz = gh[i + H], hn = gh[i + 2 * H];
        float r = 1.f / (1.f + __expf(-(ir + hr)));
        float z = 1.f / (1.f + __expf(-(iz + hz)));
        float n = tanhf(in_ + r * hn);
        float h0 = hidden[i];
        float h = (1.f - z) * n + z * h0;
        hout[i] = h;
        out_h[i] = h;
    }
}

// K4: logits = out_W @ h_new + out_b. 2 rows/wave, 256 blocks x 512.
__global__ __launch_bounds__(512) void k_out(const float* __restrict__ outW,
                                             const float* __restrict__ outB,
                                             const float* __restrict__ h,
                                             float* __restrict__ logits) {
    const int wave = threadIdx.x >> 6, lane = threadIdx.x & 63;
    const int row = blockIdx.x * 16 + wave * 2;      // 0..4094
    float r0, r1;
    wave_dot2(outW + (size_t)row * H, outW + (size_t)(row + 1) * H, h, H >> 2, lane, r0, r1);
    if (lane == 0) {
        logits[row]     = r0 + outB[row];
        logits[row + 1] = r1 + outB[row + 1];
    }
}

// K5: log_softmax over 4096 logits (L2-hot, single block).
__global__ __launch_bounds__(1024) void k_lsm(const float* __restrict__ logits,
                                              float* __restrict__ out) {
    __shared__ float red[16];
    __shared__ float red2[16];
    const int tid = threadIdx.x, lane = tid & 63, wave = tid >> 6;
    float m = -1e30f;
    for (int k = tid; k < O; k += 1024) m = fmaxf(m, logits[k]);
    #pragma unroll
    for (int off = 32; off; off >>= 1) m = fmaxf(m, __shfl_down(m, off, 64));
    if (lane == 0) red[wave] = m;
    __syncthreads();
    if (tid == 0) {
        float mm = -1e30f;
        for (int j = 0; j < 16; j++) mm = fmaxf(mm, red[j]);
        red[0] = mm;
    }
    __syncthreads();
    m = red[0];
    float s = 0.f;
    for (int k = tid; k < O; k += 1024) s += __expf(logits[k] - m);
    #pragma unroll
    for (int off = 32; off; off >>= 1) s += __shfl_down(s, off, 64);
    if (lane == 0) red2[wave] = s;
    __syncthreads();
    if (tid == 0) {
        float ss = 0.f;
        for (int j = 0; j < 16; j++) ss += red2[j];
        red2[0] = m + logf(ss);
    }
    __syncthreads();
    float lse = red2[0];
    for (int k = tid; k < O; k += 1024) out[k] = logits[k] - lse;
}

extern "C" void kernel_launch(void* const* d_in, const int* in_sizes, int n_in,
                              void* d_out, int out_size, void* d_ws, size_t ws_size,
                              hipStream_t stream) {
    const int*   ids    = (const int*)d_in[0];
    const float* hidden = (const float*)d_in[1];
    // d_in[2] (e_output) unused by the reference
    const float* eseq   = (const float*)d_in[3];
    const float* embW   = (const float*)d_in[4];
    const float* attW   = (const float*)d_in[5];
    const float* attb   = (const float*)d_in[6];
    const float* combW  = (const float*)d_in[7];
    const float* combB  = (const float*)d_in[8];
    const float* gihW   = (const float*)d_in[9];
    const float* ghhW   = (const float*)d_in[10];
    const float* gihB   = (const float*)d_in[11];
    const float* ghhB   = (const float*)d_in[12];
    const float* outW   = (const float*)d_in[13];
    const float* outB   = (const float*)d_in[14];
    float* out = (float*)d_out;   // [log_softmax(4096) | h_new(4096) | att_w(15)]

    float* ws       = (float*)d_ws;
    float* combined = ws;             // 8192
    float* xbuf     = ws + 8192;      // 4096
    float* ghbuf    = ws + 12288;     // 12288
    float* hbuf     = ws + 24576;     // 4096
    float* logits   = ws + 28672;     // 4096
    float* attlog   = ws + 32768;     // 16

    k_attlogit<<<MAXLEN, 1024, 0, stream>>>(ids, hidden, embW, attW, attb, attlog);
    k_attapply<<<16,     256,  0, stream>>>(ids, embW, attlog, eseq, combined, out + 8192);
    k_mv1     <<<1024,   512,  0, stream>>>(combW, combB, ghhW, ghhB, hidden, combined, xbuf, ghbuf);
    k_gru     <<<1024,   256,  0, stream>>>(gihW, gihB, hidden, xbuf, ghbuf, hbuf, out + 4096);
    k_out     <<<256,    512,  0, stream>>>(outW, outB, hbuf, logits);
    k_lsm     <<<1,      1024, 0, stream>>>(logits, out);
}